// Round 13
// baseline (239.053 us; speedup 1.0000x reference)
//
#include <hip/hip_runtime.h>
#include <hip/hip_bf16.h>

#define NB   32
#define SEQ  512
#define HID  768
#define FFN  3072
#define NEXP 8

typedef float f32x4 __attribute__((ext_vector_type(4)));
typedef short s16x8 __attribute__((ext_vector_type(8)));

__device__ __forceinline__ unsigned short f2bf(float f) {
    return __builtin_bit_cast(unsigned short, (__bf16)f);
}

__device__ __forceinline__ float fast_exp2(float x) {
    float r; asm("v_exp_f32 %0, %1" : "=v"(r) : "v"(x)); return r;
}
__device__ __forceinline__ float fast_rcp(float x) {
    float r; asm("v_rcp_f32 %0, %1" : "=v"(r) : "v"(x)); return r;
}

// tanh-gelu, overflow-free (exp2 arg <= 0). |error| vs exact-erf gelu ~2e-4.
__device__ __forceinline__ float gelu_fast(float v) {
    float u  = v * (0.7978845608f + 0.0356774081f * v * v);
    float t  = fast_exp2(-2.8853900817779268f * fabsf(u));
    float T  = (1.0f - t) * fast_rcp(1.0f + t);
    return 0.5f * v + 0.5f * fabsf(v) * T;
}

#define GLOAD16(gp, lp) __builtin_amdgcn_global_load_lds( \
    (const __attribute__((address_space(1))) unsigned int*)(gp), \
    (__attribute__((address_space(3))) unsigned int*)(lp), 16, 0, 0)

#define VMCNT(N) asm volatile("s_waitcnt vmcnt(%0)" :: "i"(N) : "memory")

// ===========================================================================
// Packed tile layout (per 256x64-elem K-tile, 32768 B):
//   [half(2)][rr(128)][q(128 B)]  with pre-applied XOR swizzle:
//   byte q of row holds tile[row][q ^ ((row&7)<<4)].
//   A-map: row = (rr&63) + ((rr>>6)<<7) + half*64
//   B-map: row = (rr&31) + ((rr>>5)<<6) + half*32
// Staging then is a PURE LINEAR copy; LDS image identical to the R10 kernel.
// ===========================================================================

// ---------------------------------------------------------------------------
// stable counting-sort permutation of sentences by expert label (1 wave)
// ---------------------------------------------------------------------------
__global__ void sort_labels_kernel(const int* __restrict__ labels, int* __restrict__ perm)
{
    int i = threadIdx.x;
    if (i < NB) {
        int li = labels[i];
        int rank = 0;
        for (int j = 0; j < NB; j++) {
            int lj = labels[j];
            if (lj < li || (lj == li && j < i)) rank++;
        }
        perm[rank] = i;
    }
}

// ---------------------------------------------------------------------------
// X fp32 -> packed-A bf16 tiles. One block per (bs, mt, kt) tile (768 blocks).
// ---------------------------------------------------------------------------
__global__ __launch_bounds__(256) void cvt_x_pack(
    const float* __restrict__ X, unsigned short* __restrict__ XbP)
{
    const int b  = blockIdx.x;            // bs*24 + mt*12 + kt
    const int kt = b % 12;
    const int mt = (b / 12) & 1;
    const int bs = b / 24;
    const float* src = X + ((size_t)bs * SEQ + (size_t)mt * 256) * HID + kt * 64;
    char* out = (char*)XbP + (size_t)b * 32768;

#pragma unroll
    for (int i = 0; i < 8; i++) {
        int c = threadIdx.x + i * 256;    // 0..2047 (16-B chunks)
        int half = c >> 10;
        int rr   = (c >> 3) & 127;
        int c16  = c & 7;
        int row  = (rr & 63) + ((rr >> 6) << 7) + half * 64;   // A-map
        int tb   = (c16 * 16) ^ ((row & 7) << 4);
        int k0e  = tb >> 1;               // element index, multiple of 8
        const float* sp = src + (size_t)row * HID + k0e;
        f32x4 a = *(const f32x4*)sp;
        f32x4 b4 = *(const f32x4*)(sp + 4);
        unsigned short o[8];
#pragma unroll
        for (int v = 0; v < 4; v++) o[v] = f2bf(a[v]);
#pragma unroll
        for (int v = 0; v < 4; v++) o[4 + v] = f2bf(b4[v]);
        *(s16x8*)(out + (size_t)c * 16) = *(s16x8*)o;
    }
}

// ---------------------------------------------------------------------------
// W [E][R][C] fp32 -> packed-B bf16 tiles [e][C/256][R/64].
// grid (C/64, R/64, E). 64x64 transpose piece via LDS.
// ---------------------------------------------------------------------------
__global__ __launch_bounds__(256) void cvt_w_pack(
    const float* __restrict__ W, unsigned short* __restrict__ WP)
{
    __shared__ unsigned short tile[64][65];
    const int e   = blockIdx.z;
    const int C   = gridDim.x * 64;
    const int R   = gridDim.y * 64;
    const int cbg = blockIdx.x * 64;      // N-offset
    const int rbg = blockIdx.y * 64;      // K-offset
    const float* src = W + (size_t)e * R * C;
    const int x = threadIdx.x & 63, y0 = threadIdx.x >> 6;
#pragma unroll
    for (int i = 0; i < 16; i++) {
        int r = y0 + i * 4;
        tile[r][x] = f2bf(src[(size_t)(rbg + r) * C + cbg + x]);   // tile[k][n]
    }
    __syncthreads();

    const int nt  = blockIdx.x >> 2;
    const int NTn = gridDim.x >> 2;
    const int kt  = blockIdx.y;
    const int KT  = gridDim.y;
    char* out = (char*)WP + ((size_t)(e * NTn + nt) * KT + kt) * 32768;

#pragma unroll
    for (int i = 0; i < 2; i++) {
        int cc  = threadIdx.x + i * 256;  // 0..511
        int n64 = cc >> 3, kc = cc & 7;
        int row = (blockIdx.x & 3) * 64 + n64;                     // n_local 0..255
        int half = (row >> 5) & 1;
        int rr   = (row & 31) | (((row >> 6) & 3) << 5);           // B-map inverse
        int q    = (kc * 16) ^ ((row & 7) << 4);
        unsigned short o[8];
#pragma unroll
        for (int j = 0; j < 8; j++) o[j] = tile[kc * 8 + j][n64];
        *(s16x8*)(out + half * 16384 + rr * 128 + q) = *(s16x8*)o;
    }
}

// ---------------------------------------------------------------------------
// Linear staging of one 16-KB region from a packed tile. Dest row-mapping
// reproduces the exact LDS image of the R10 kernel.
// ---------------------------------------------------------------------------
template<bool ISA>
__device__ __forceinline__ void stage_lin(const char* tile, char* lds, int half, int tid)
{
#pragma unroll
    for (int p = 0; p < 2; p++) {
        int L  = p * 8192 + tid * 16;
        int rr = L >> 7;
        int cb = L & 127;
        int row = ISA ? ((rr & 63) + ((rr >> 6) << 7) + half * 64)
                      : ((rr & 31) + ((rr >> 5) << 6) + half * 32);
        GLOAD16(tile + half * 16384 + L, lds + (size_t)row * 128 + cb);
    }
}

__device__ __forceinline__ void read_af(const char* Ab, int arow_b, int k0, int ih, s16x8 (&a)[2][4])
{
    const int k1 = k0 ^ 64;
#pragma unroll
    for (int i = 0; i < 4; i++) {
        const char* p = Ab + arow_b + (ih * 64 + i * 16) * 128;
        a[0][i] = *(const s16x8*)(p + k0);
        a[1][i] = *(const s16x8*)(p + k1);
    }
}
__device__ __forceinline__ void read_bf(const char* Bb, int brow_b, int k0, int jh, s16x8 (&b)[2][2])
{
    const int k1 = k0 ^ 64;
#pragma unroll
    for (int j = 0; j < 2; j++) {
        const char* p = Bb + brow_b + (jh * 32 + j * 16) * 128;
        b[0][j] = *(const s16x8*)(p + k0);
        b[1][j] = *(const s16x8*)(p + k1);
    }
}

template<int IH, int JH>
__device__ __forceinline__ void mfma_quad(s16x8 (&a)[2][4], s16x8 (&b)[2][2], f32x4 (&acc)[8][4])
{
    __builtin_amdgcn_s_setprio(1);
#pragma unroll
    for (int kk = 0; kk < 2; kk++)
#pragma unroll
        for (int i = 0; i < 4; i++)
#pragma unroll
            for (int j = 0; j < 2; j++)
                acc[IH * 4 + i][JH * 2 + j] = __builtin_amdgcn_mfma_f32_16x16x32_bf16(
                    a[kk][i], b[kk][j], acc[IH * 4 + i][JH * 2 + j], 0, 0, 0);
    __builtin_amdgcn_s_setprio(0);
}

template<bool S1, bool S2, int VM>
__device__ __forceinline__ void gwindowT(
    const char* tA1, const char* tB1, const char* tA0, const char* tB0,
    char* Acur, char* Bcur, char* Anxt, char* Bnxt,
    int arow_b, int brow_b, int k0, int tid, f32x4 (&acc)[8][4])
{
    s16x8 a[2][4], b0[2][2], b1[2][2];
    read_af(Acur, arow_b, k0, 0, a);
    read_bf(Bcur, brow_b, k0, 0, b0);
    if constexpr (S1) stage_lin<true >(tA1, Anxt, 1, tid);
    __builtin_amdgcn_s_barrier();
    mfma_quad<0, 0>(a, b0, acc);
    __builtin_amdgcn_s_barrier();
    read_bf(Bcur, brow_b, k0, 1, b1);
    if constexpr (S1) stage_lin<false>(tB1, Bnxt, 1, tid);
    __builtin_amdgcn_s_barrier();
    mfma_quad<0, 1>(a, b1, acc);
    __builtin_amdgcn_s_barrier();
    read_af(Acur, arow_b, k0, 1, a);
    if constexpr (S2) stage_lin<true >(tA0, Acur, 0, tid);
    __builtin_amdgcn_s_barrier();
    mfma_quad<1, 1>(a, b1, acc);
    __builtin_amdgcn_s_barrier();
    if constexpr (S2) stage_lin<false>(tB0, Bcur, 0, tid);
    __builtin_amdgcn_s_barrier();
    mfma_quad<1, 0>(a, b0, acc);
    if constexpr (VM >= 0) VMCNT(VM);
    __builtin_amdgcn_s_barrier();
}

__device__ __forceinline__ void mainloopT(const char* At, const char* Bt, int KT,
    char* smem, int tid, int arow_b, int brow_b, int k0, f32x4 (&acc)[8][4])
{
    stage_lin<true >(At,          smem,          0, tid);
    stage_lin<false>(Bt,          smem + 65536,  0, tid);
    stage_lin<true >(At,          smem,          1, tid);
    stage_lin<false>(Bt,          smem + 65536,  1, tid);
    stage_lin<true >(At + 32768,  smem + 32768,  0, tid);
    stage_lin<false>(Bt + 32768,  smem + 98304,  0, tid);
    VMCNT(4);
    __builtin_amdgcn_s_barrier();

    int cur = 0;
    for (int kt = 0; kt < KT - 2; ++kt) {
        char* Ac = smem + (cur << 15);
        char* An = smem + ((cur ^ 1) << 15);
        char* Bc = smem + 65536 + (cur << 15);
        char* Bn = smem + 65536 + ((cur ^ 1) << 15);
        gwindowT<true, true, 4>(At + (size_t)(kt + 1) * 32768, Bt + (size_t)(kt + 1) * 32768,
                                At + (size_t)(kt + 2) * 32768, Bt + (size_t)(kt + 2) * 32768,
                                Ac, Bc, An, Bn, arow_b, brow_b, k0, tid, acc);
        cur ^= 1;
    }
    {
        char* Ac = smem + (cur << 15);
        char* An = smem + ((cur ^ 1) << 15);
        char* Bc = smem + 65536 + (cur << 15);
        char* Bn = smem + 65536 + ((cur ^ 1) << 15);
        gwindowT<true, false, 0>(At + (size_t)(KT - 1) * 32768, Bt + (size_t)(KT - 1) * 32768,
                                 nullptr, nullptr, Ac, Bc, An, Bn, arow_b, brow_b, k0, tid, acc);
        cur ^= 1;
    }
    {
        char* Ac = smem + (cur << 15);
        char* An = smem + ((cur ^ 1) << 15);
        char* Bc = smem + 65536 + (cur << 15);
        char* Bn = smem + 65536 + ((cur ^ 1) << 15);
        gwindowT<false, false, -1>(nullptr, nullptr, nullptr, nullptr,
                                   Ac, Bc, An, Bn, arow_b, brow_b, k0, tid, acc);
    }
}

// ---------------------------------------------------------------------------
// Kernel 1: G = gelu(XbP @ W1P[e] + b1[e]) -> packed-A GP tiles (for gemm2).
// R10 banding (768 blocks); epilogue: LDS swizzled tile -> linear NT stream
// into GP (epilogue swizzle and tile swizzle cancel exactly).
// ---------------------------------------------------------------------------
__global__ __launch_bounds__(512, 2) void moe_gemm1(
    const unsigned short* __restrict__ XbP,
    const int*   __restrict__ labels,
    const int*   __restrict__ perm,
    const unsigned short* __restrict__ W1P,
    const float* __restrict__ B1,
    unsigned short* __restrict__ GP)
{
    extern __shared__ char smem[];
    const int L = blockIdx.x;
    const int xcd  = L & 7;
    const int r    = L >> 8;          // band 0..2
    const int i    = (L >> 3) & 31;
    const int pair = i >> 2;          // 0..7
    const int bs = perm[xcd * 4 + (pair >> 1)];
    const int mt = pair & 1;
    const int nt = r * 4 + (i & 3);
    const int e  = labels[bs];

    const char* At = (const char*)XbP + (size_t)((bs * 2 + mt) * 12) * 32768;
    const char* Bt = (const char*)W1P + (size_t)((e * 12 + nt) * 12) * 32768;

    const int tid = threadIdx.x;
    const int lane = tid & 63, w = tid >> 6;
    const int wm = (w >> 2) * 128, wn = (w & 3) * 64;
    const int fr = lane & 15, fq = lane >> 4;
    const int arow_b = (wm + fr) * 128, brow_b = (wn + fr) * 128;
    const int k0 = (fq * 16) ^ ((fr & 7) << 4);

    f32x4 acc[8][4];
#pragma unroll
    for (int i2 = 0; i2 < 8; i2++)
#pragma unroll
        for (int j = 0; j < 4; j++) acc[i2][j] = (f32x4)0.0f;

    mainloopT(At, Bt, 12, smem, tid, arow_b, brow_b, k0, acc);

    // ---- epilogue: bias+gelu -> LDS [256][512B] swizzled ----
    const float* b1g = B1 + (size_t)e * FFN + (size_t)nt * 256;
    float bias[4];
#pragma unroll
    for (int nj = 0; nj < 4; nj++) bias[nj] = b1g[wn + nj * 16 + fr];
#pragma unroll
    for (int mi = 0; mi < 8; mi++)
#pragma unroll
        for (int nj = 0; nj < 4; nj++) {
            const int col = wn + nj * 16 + fr;
#pragma unroll
            for (int r2 = 0; r2 < 4; r2++) {
                const int row = wm + mi * 16 + fq * 4 + r2;
                float v = acc[mi][nj][r2] + bias[nj];
                int byte = row * 512 + ((col * 2) ^ ((row & 7) << 4));
                *(unsigned short*)(smem + byte) = f2bf(gelu_fast(v));
            }
        }
    __syncthreads();
    // ---- stream out: linear NT into packed GP (4 kt2 tiles) ----
    char* GPb = (char*)GP + ((size_t)(bs * 2 + mt) * 48 + (size_t)nt * 4) * 32768;
#pragma unroll
    for (int it = 0; it < 16; it++) {
        int c2 = tid + it * 512;          // 0..8191
        int kt2l = c2 >> 11;
        int reg  = (c2 >> 10) & 1;
        int rr2  = (c2 >> 3) & 127;
        int c16  = c2 & 7;
        int row  = (rr2 & 63) + ((rr2 >> 6) << 7) + reg * 64;    // A-map
        s16x8 v = *(const s16x8*)(smem + row * 512 + kt2l * 128 + c16 * 16);
        __builtin_nontemporal_store(v,
            (s16x8*)(GPb + (size_t)kt2l * 32768 + (size_t)(c2 & 2047) * 16));
    }
}

// ---------------------------------------------------------------------------
// Kernel 2: Out = GP @ W2P[e] + b2[e] -> fp32 (normal layout, NT epilogue)
// ---------------------------------------------------------------------------
__global__ __launch_bounds__(512, 2) void moe_gemm2(
    const unsigned short* __restrict__ GP,
    const int*   __restrict__ labels,
    const int*   __restrict__ perm,
    const unsigned short* __restrict__ W2P,
    const float* __restrict__ B2,
    float* __restrict__ Out)
{
    extern __shared__ char smem[];
    const int L = blockIdx.x;
    const int xcd = L & 7, s = L >> 3;    // s in [0,24)
    const int bs = perm[xcd * 4 + s / 6];
    const int rr = s % 6;
    const int mt = rr / 3, nt = rr % 3;
    const int e  = labels[bs];

    const char* At = (const char*)GP  + (size_t)((bs * 2 + mt) * 48) * 32768;
    const char* Bt = (const char*)W2P + (size_t)((e * 3 + nt) * 48) * 32768;

    const int tid = threadIdx.x;
    const int lane = tid & 63, w = tid >> 6;
    const int wm = (w >> 2) * 128, wn = (w & 3) * 64;
    const int fr = lane & 15, fq = lane >> 4;
    const int arow_b = (wm + fr) * 128, brow_b = (wn + fr) * 128;
    const int k0 = (fq * 16) ^ ((fr & 7) << 4);

    f32x4 acc[8][4];
#pragma unroll
    for (int i = 0; i < 8; i++)
#pragma unroll
        for (int j = 0; j < 4; j++) acc[i][j] = (f32x4)0.0f;

    mainloopT(At, Bt, 48, smem, tid, arow_b, brow_b, k0, acc);

    const float* b2g = B2 + (size_t)e * HID + (size_t)nt * 256;
    float bias[4];
#pragma unroll
    for (int nj = 0; nj < 4; nj++) bias[nj] = b2g[wn + nj * 16 + fr];
    char* Cgb = (char*)(Out + ((size_t)bs * SEQ + (size_t)mt * 256) * HID + (size_t)nt * 256);

#pragma unroll
    for (int half = 0; half < 2; ++half) {
        if ((wn >> 7) == half) {
#pragma unroll
            for (int mi = 0; mi < 8; mi++)
#pragma unroll
                for (int nj = 0; nj < 4; nj++) {
                    const int lcol = (wn & 127) + nj * 16 + fr;
#pragma unroll
                    for (int r2 = 0; r2 < 4; r2++) {
                        const int row = wm + mi * 16 + fq * 4 + r2;
                        int byte = row * 512 + ((lcol * 4) ^ ((row & 7) << 4));
                        *(float*)(smem + byte) = acc[mi][nj][r2] + bias[nj];
                    }
                }
        }
        __syncthreads();
#pragma unroll
        for (int it = 0; it < 16; it++) {
            int chunk = tid + it * 512;
            int row = chunk >> 5;
            int cb  = (chunk & 31) * 16;
            f32x4 v = *(const f32x4*)(smem + row * 512 + (cb ^ ((row & 7) << 4)));
            __builtin_nontemporal_store(v, (f32x4*)(Cgb + (size_t)row * (HID * 4) + half * 512 + cb));
        }
        if (half == 0) __syncthreads();
    }
}

extern "C" void kernel_launch(void* const* d_in, const int* in_sizes, int n_in,
                              void* d_out, int out_size, void* d_ws, size_t ws_size,
                              hipStream_t stream) {
    const float* X      = (const float*)d_in[0];
    const int*   labels = (const int*)  d_in[1];
    const float* W1     = (const float*)d_in[2];
    const float* B1     = (const float*)d_in[3];
    const float* W2     = (const float*)d_in[4];
    const float* B2     = (const float*)d_in[5];
    float* Out = (float*)d_out;

    char* ws = (char*)d_ws;
    unsigned short* XbP = (unsigned short*)(ws);               // 25,165,824 B (uses 24 MB)
    unsigned short* W1P = (unsigned short*)(ws + 25165824);    // 37,748,736 B (uses 36 MB)
    unsigned short* W2P = (unsigned short*)(ws + 62914560);    // 37,748,736 B (uses 36 MB)
    unsigned short* GP  = (unsigned short*)(ws + 100663296);   // 100,663,296 B (uses 96 MB)
    int*            perm = (int*)(ws + 201326592);             // 128 B

    (void)hipFuncSetAttribute((const void*)moe_gemm1,
        hipFuncAttributeMaxDynamicSharedMemorySize, 131072);
    (void)hipFuncSetAttribute((const void*)moe_gemm2,
        hipFuncAttributeMaxDynamicSharedMemorySize, 131072);

    sort_labels_kernel<<<1, 64, 0, stream>>>(labels, perm);
    cvt_x_pack<<<768, 256, 0, stream>>>(X, XbP);
    cvt_w_pack<<<dim3(FFN / 64, HID / 64, NEXP), 256, 0, stream>>>(W1, W1P);  // C=FFN, R=HID
    cvt_w_pack<<<dim3(HID / 64, FFN / 64, NEXP), 256, 0, stream>>>(W2, W2P);  // C=HID, R=FFN

    moe_gemm1<<<768, dim3(512), 131072, stream>>>(XbP, labels, perm, W1P, B1, GP);
    moe_gemm2<<<192, dim3(512), 131072, stream>>>(GP, labels, perm, W2P, B2, Out);
}

// Round 14
// 233.525 us; speedup vs baseline: 1.0237x; 1.0237x over previous
//
#include <hip/hip_runtime.h>
#include <hip/hip_bf16.h>

#define NB   32
#define SEQ  512
#define HID  768
#define FFN  3072
#define NEXP 8

typedef float f32x4 __attribute__((ext_vector_type(4)));
typedef short s16x8 __attribute__((ext_vector_type(8)));

__device__ __forceinline__ unsigned short f2bf(float f) {
    return __builtin_bit_cast(unsigned short, (__bf16)f);
}

__device__ __forceinline__ float fast_exp2(float x) {
    float r; asm("v_exp_f32 %0, %1" : "=v"(r) : "v"(x)); return r;
}
__device__ __forceinline__ float fast_rcp(float x) {
    float r; asm("v_rcp_f32 %0, %1" : "=v"(r) : "v"(x)); return r;
}

// tanh-gelu, overflow-free (exp2 arg <= 0). |error| vs exact-erf gelu ~2e-4.
__device__ __forceinline__ float gelu_fast(float v) {
    float u  = v * (0.7978845608f + 0.0356774081f * v * v);
    float t  = fast_exp2(-2.8853900817779268f * fabsf(u));
    float T  = (1.0f - t) * fast_rcp(1.0f + t);
    return 0.5f * v + 0.5f * fabsf(v) * T;
}

#define GLOAD16(gp, lp) __builtin_amdgcn_global_load_lds( \
    (const __attribute__((address_space(1))) unsigned int*)(gp), \
    (__attribute__((address_space(3))) unsigned int*)(lp), 16, 0, 0)

#define VMCNT(N) asm volatile("s_waitcnt vmcnt(%0)" :: "i"(N) : "memory")

// ===========================================================================
// Packed tile layout (per 256x64-elem K-tile, 32768 B):
//   [half(2)][rr(128)][q(128 B)] with pre-applied XOR swizzle (see R13).
//   A-map: row = (rr&63) + ((rr>>6)<<7) + half*64
//   B-map: row = (rr&31) + ((rr>>5)<<6) + half*32
// ===========================================================================

// ---------------------------------------------------------------------------
// cvt_w body: W [E][R][C] fp32 -> packed-B tiles [e][C/256][R/64]
// ---------------------------------------------------------------------------
__device__ __forceinline__ void cvt_w_body(
    const float* __restrict__ W, unsigned short* __restrict__ WP,
    unsigned short (*tile)[65], int nx, int ny, int bx, int by, int bz)
{
    const int C = nx * 64, R = ny * 64;
    const int cbg = bx * 64, rbg = by * 64;
    const float* src = W + (size_t)bz * R * C;
    const int x = threadIdx.x & 63, y0 = threadIdx.x >> 6;
#pragma unroll
    for (int i = 0; i < 16; i++) {
        int r = y0 + i * 4;
        tile[r][x] = f2bf(src[(size_t)(rbg + r) * C + cbg + x]);   // tile[k][n]
    }
    __syncthreads();

    const int nt  = bx >> 2;
    const int NTn = nx >> 2;
    const int kt  = by;
    const int KT  = ny;
    char* out = (char*)WP + ((size_t)(bz * NTn + nt) * KT + kt) * 32768;

#pragma unroll
    for (int i = 0; i < 2; i++) {
        int cc  = threadIdx.x + i * 256;  // 0..511
        int n64 = cc >> 3, kc = cc & 7;
        int row = (bx & 3) * 64 + n64;                             // n_local 0..255
        int half = (row >> 5) & 1;
        int rr   = (row & 31) | (((row >> 6) & 3) << 5);           // B-map inverse
        int q    = (kc * 16) ^ ((row & 7) << 4);
        unsigned short o[8];
#pragma unroll
        for (int j = 0; j < 8; j++) o[j] = tile[kc * 8 + j][n64];
        *(s16x8*)(out + half * 16384 + rr * 128 + q) = *(s16x8*)o;
    }
}

// ---------------------------------------------------------------------------
// Merged prep: block 0 = label sort; 1..768 = X->packed-A; then W1, W2 packs.
// ---------------------------------------------------------------------------
__global__ __launch_bounds__(256) void prep_all(
    const float* __restrict__ X, const float* __restrict__ W1,
    const float* __restrict__ W2, const int* __restrict__ labels,
    unsigned short* __restrict__ XbP, unsigned short* __restrict__ W1P,
    unsigned short* __restrict__ W2P, int* __restrict__ perm)
{
    __shared__ unsigned short tile[64][65];
    const int bid = blockIdx.x;
    if (bid == 0) {
        int i = threadIdx.x;
        if (i < NB) {
            int li = labels[i];
            int rank = 0;
            for (int j = 0; j < NB; j++) {
                int lj = labels[j];
                if (lj < li || (lj == li && j < i)) rank++;
            }
            perm[rank] = i;
        }
        return;
    }
    if (bid <= 768) {
        const int b  = bid - 1;           // bs*24 + mt*12 + kt
        const int kt = b % 12;
        const int mt = (b / 12) & 1;
        const int bs = b / 24;
        const float* src = X + ((size_t)bs * SEQ + (size_t)mt * 256) * HID + kt * 64;
        char* out = (char*)XbP + (size_t)b * 32768;
#pragma unroll
        for (int i = 0; i < 8; i++) {
            int c = threadIdx.x + i * 256;
            int half = c >> 10;
            int rr   = (c >> 3) & 127;
            int c16  = c & 7;
            int row  = (rr & 63) + ((rr >> 6) << 7) + half * 64;   // A-map
            int tb   = (c16 * 16) ^ ((row & 7) << 4);
            const float* sp = src + (size_t)row * HID + (tb >> 1);
            f32x4 a = *(const f32x4*)sp;
            f32x4 b4 = *(const f32x4*)(sp + 4);
            unsigned short o[8];
#pragma unroll
            for (int v = 0; v < 4; v++) o[v] = f2bf(a[v]);
#pragma unroll
            for (int v = 0; v < 4; v++) o[4 + v] = f2bf(b4[v]);
            *(s16x8*)(out + (size_t)c * 16) = *(s16x8*)o;
        }
        return;
    }
    if (bid <= 768 + 4608) {              // W1: (nx=48, ny=12, E)
        int idx = bid - 769;
        cvt_w_body(W1, W1P, tile, 48, 12, idx % 48, (idx / 48) % 12, idx / 576);
        return;
    }
    {                                     // W2: (nx=12, ny=48, E)
        int idx = bid - (769 + 4608);
        cvt_w_body(W2, W2P, tile, 12, 48, idx % 12, (idx / 12) % 48, idx / 576);
    }
}

// ---------------------------------------------------------------------------
// Linear staging of one 16-KB region from a packed tile (R13, unchanged).
// ---------------------------------------------------------------------------
template<bool ISA>
__device__ __forceinline__ void stage_lin(const char* tile, char* lds, int half, int tid)
{
#pragma unroll
    for (int p = 0; p < 2; p++) {
        int L  = p * 8192 + tid * 16;
        int rr = L >> 7;
        int cb = L & 127;
        int row = ISA ? ((rr & 63) + ((rr >> 6) << 7) + half * 64)
                      : ((rr & 31) + ((rr >> 5) << 6) + half * 32);
        GLOAD16(tile + half * 16384 + L, lds + (size_t)row * 128 + cb);
    }
}

__device__ __forceinline__ void read_af(const char* Ab, int arow_b, int k0, int ih, s16x8 (&a)[2][4])
{
    const int k1 = k0 ^ 64;
#pragma unroll
    for (int i = 0; i < 4; i++) {
        const char* p = Ab + arow_b + (ih * 64 + i * 16) * 128;
        a[0][i] = *(const s16x8*)(p + k0);
        a[1][i] = *(const s16x8*)(p + k1);
    }
}
__device__ __forceinline__ void read_bf(const char* Bb, int brow_b, int k0, int jh, s16x8 (&b)[2][2])
{
    const int k1 = k0 ^ 64;
#pragma unroll
    for (int j = 0; j < 2; j++) {
        const char* p = Bb + brow_b + (jh * 32 + j * 16) * 128;
        b[0][j] = *(const s16x8*)(p + k0);
        b[1][j] = *(const s16x8*)(p + k1);
    }
}

template<int IH, int JH>
__device__ __forceinline__ void mfma_quad(s16x8 (&a)[2][4], s16x8 (&b)[2][2], f32x4 (&acc)[8][4])
{
    __builtin_amdgcn_s_setprio(1);
#pragma unroll
    for (int kk = 0; kk < 2; kk++)
#pragma unroll
        for (int i = 0; i < 4; i++)
#pragma unroll
            for (int j = 0; j < 2; j++)
                acc[IH * 4 + i][JH * 2 + j] = __builtin_amdgcn_mfma_f32_16x16x32_bf16(
                    a[kk][i], b[kk][j], acc[IH * 4 + i][JH * 2 + j], 0, 0, 0);
    __builtin_amdgcn_s_setprio(0);
}

template<bool S1, bool S2, int VM>
__device__ __forceinline__ void gwindowT(
    const char* tA1, const char* tB1, const char* tA0, const char* tB0,
    char* Acur, char* Bcur, char* Anxt, char* Bnxt,
    int arow_b, int brow_b, int k0, int tid, f32x4 (&acc)[8][4])
{
    s16x8 a[2][4], b0[2][2], b1[2][2];
    read_af(Acur, arow_b, k0, 0, a);
    read_bf(Bcur, brow_b, k0, 0, b0);
    if constexpr (S1) stage_lin<true >(tA1, Anxt, 1, tid);
    __builtin_amdgcn_s_barrier();
    mfma_quad<0, 0>(a, b0, acc);
    __builtin_amdgcn_s_barrier();
    read_bf(Bcur, brow_b, k0, 1, b1);
    if constexpr (S1) stage_lin<false>(tB1, Bnxt, 1, tid);
    __builtin_amdgcn_s_barrier();
    mfma_quad<0, 1>(a, b1, acc);
    __builtin_amdgcn_s_barrier();
    read_af(Acur, arow_b, k0, 1, a);
    if constexpr (S2) stage_lin<true >(tA0, Acur, 0, tid);
    __builtin_amdgcn_s_barrier();
    mfma_quad<1, 1>(a, b1, acc);
    __builtin_amdgcn_s_barrier();
    if constexpr (S2) stage_lin<false>(tB0, Bcur, 0, tid);
    __builtin_amdgcn_s_barrier();
    mfma_quad<1, 0>(a, b0, acc);
    if constexpr (VM >= 0) VMCNT(VM);
    __builtin_amdgcn_s_barrier();
}

// K-rotated mainloop: logical window k uses physical tile (k+off)%KT.
__device__ __forceinline__ void mainloopT(const char* At, const char* Bt, int KT, int off,
    char* smem, int tid, int arow_b, int brow_b, int k0, f32x4 (&acc)[8][4])
{
    auto TI = [&](int k) -> size_t {
        int kk = k + off; if (kk >= KT) kk -= KT;
        return (size_t)kk * 32768;
    };
    stage_lin<true >(At + TI(0),  smem,          0, tid);
    stage_lin<false>(Bt + TI(0),  smem + 65536,  0, tid);
    stage_lin<true >(At + TI(0),  smem,          1, tid);
    stage_lin<false>(Bt + TI(0),  smem + 65536,  1, tid);
    stage_lin<true >(At + TI(1),  smem + 32768,  0, tid);
    stage_lin<false>(Bt + TI(1),  smem + 98304,  0, tid);
    VMCNT(4);
    __builtin_amdgcn_s_barrier();

    int cur = 0;
    for (int kt = 0; kt < KT - 2; ++kt) {
        char* Ac = smem + (cur << 15);
        char* An = smem + ((cur ^ 1) << 15);
        char* Bc = smem + 65536 + (cur << 15);
        char* Bn = smem + 65536 + ((cur ^ 1) << 15);
        gwindowT<true, true, 4>(At + TI(kt + 1), Bt + TI(kt + 1),
                                At + TI(kt + 2), Bt + TI(kt + 2),
                                Ac, Bc, An, Bn, arow_b, brow_b, k0, tid, acc);
        cur ^= 1;
    }
    {
        char* Ac = smem + (cur << 15);
        char* An = smem + ((cur ^ 1) << 15);
        char* Bc = smem + 65536 + (cur << 15);
        char* Bn = smem + 65536 + ((cur ^ 1) << 15);
        gwindowT<true, false, 0>(At + TI(KT - 1), Bt + TI(KT - 1),
                                 nullptr, nullptr, Ac, Bc, An, Bn, arow_b, brow_b, k0, tid, acc);
        cur ^= 1;
    }
    {
        char* Ac = smem + (cur << 15);
        char* An = smem + ((cur ^ 1) << 15);
        char* Bc = smem + 65536 + (cur << 15);
        char* Bn = smem + 65536 + ((cur ^ 1) << 15);
        gwindowT<false, false, -1>(nullptr, nullptr, nullptr, nullptr,
                                   Ac, Bc, An, Bn, arow_b, brow_b, k0, tid, acc);
    }
}

// ---------------------------------------------------------------------------
// Kernel 1: G = gelu(XbP @ W1P[e] + b1[e]) -> packed-A GP tiles.
// R10 banding + K-rotation stagger off = (pair + c*3) % 12: breaks sharer
// lockstep so B-sharers arrive 1 window apart (A: 3 apart) -> L2 hits.
// ---------------------------------------------------------------------------
__global__ __launch_bounds__(512, 2) void moe_gemm1(
    const unsigned short* __restrict__ XbP,
    const int*   __restrict__ labels,
    const int*   __restrict__ perm,
    const unsigned short* __restrict__ W1P,
    const float* __restrict__ B1,
    unsigned short* __restrict__ GP)
{
    extern __shared__ char smem[];
    const int L = blockIdx.x;
    const int xcd  = L & 7;
    const int r    = L >> 8;          // band 0..2
    const int i    = (L >> 3) & 31;
    const int pair = i >> 2;          // 0..7
    const int c    = i & 3;
    const int bs = perm[xcd * 4 + (pair >> 1)];
    const int mt = pair & 1;
    const int nt = r * 4 + c;
    const int e  = labels[bs];
    const int off = (pair + c * 3) % 12;

    const char* At = (const char*)XbP + (size_t)((bs * 2 + mt) * 12) * 32768;
    const char* Bt = (const char*)W1P + (size_t)((e * 12 + nt) * 12) * 32768;

    const int tid = threadIdx.x;
    const int lane = tid & 63, w = tid >> 6;
    const int wm = (w >> 2) * 128, wn = (w & 3) * 64;
    const int fr = lane & 15, fq = lane >> 4;
    const int arow_b = (wm + fr) * 128, brow_b = (wn + fr) * 128;
    const int k0 = (fq * 16) ^ ((fr & 7) << 4);

    f32x4 acc[8][4];
#pragma unroll
    for (int i2 = 0; i2 < 8; i2++)
#pragma unroll
        for (int j = 0; j < 4; j++) acc[i2][j] = (f32x4)0.0f;

    mainloopT(At, Bt, 12, off, smem, tid, arow_b, brow_b, k0, acc);

    // ---- epilogue: bias+gelu -> LDS [256][512B] swizzled ----
    const float* b1g = B1 + (size_t)e * FFN + (size_t)nt * 256;
    float bias[4];
#pragma unroll
    for (int nj = 0; nj < 4; nj++) bias[nj] = b1g[wn + nj * 16 + fr];
#pragma unroll
    for (int mi = 0; mi < 8; mi++)
#pragma unroll
        for (int nj = 0; nj < 4; nj++) {
            const int col = wn + nj * 16 + fr;
#pragma unroll
            for (int r2 = 0; r2 < 4; r2++) {
                const int row = wm + mi * 16 + fq * 4 + r2;
                float v = acc[mi][nj][r2] + bias[nj];
                int byte = row * 512 + ((col * 2) ^ ((row & 7) << 4));
                *(unsigned short*)(smem + byte) = f2bf(gelu_fast(v));
            }
        }
    __syncthreads();
    // ---- stream out: linear NT into packed GP (4 kt2 tiles) ----
    char* GPb = (char*)GP + ((size_t)(bs * 2 + mt) * 48 + (size_t)nt * 4) * 32768;
#pragma unroll
    for (int it = 0; it < 16; it++) {
        int c2 = tid + it * 512;          // 0..8191
        int kt2l = c2 >> 11;
        int reg  = (c2 >> 10) & 1;
        int rr2  = (c2 >> 3) & 127;
        int c16  = c2 & 7;
        int row  = (rr2 & 63) + ((rr2 >> 6) << 7) + reg * 64;    // A-map
        s16x8 v = *(const s16x8*)(smem + row * 512 + kt2l * 128 + c16 * 16);
        __builtin_nontemporal_store(v,
            (s16x8*)(GPb + (size_t)kt2l * 32768 + (size_t)(c2 & 2047) * 16));
    }
}

// ---------------------------------------------------------------------------
// Kernel 2: Out = GP @ W2P[e] + b2[e] -> fp32 (unchanged control, off=0)
// ---------------------------------------------------------------------------
__global__ __launch_bounds__(512, 2) void moe_gemm2(
    const unsigned short* __restrict__ GP,
    const int*   __restrict__ labels,
    const int*   __restrict__ perm,
    const unsigned short* __restrict__ W2P,
    const float* __restrict__ B2,
    float* __restrict__ Out)
{
    extern __shared__ char smem[];
    const int L = blockIdx.x;
    const int xcd = L & 7, s = L >> 3;    // s in [0,24)
    const int bs = perm[xcd * 4 + s / 6];
    const int rr = s % 6;
    const int mt = rr / 3, nt = rr % 3;
    const int e  = labels[bs];

    const char* At = (const char*)GP  + (size_t)((bs * 2 + mt) * 48) * 32768;
    const char* Bt = (const char*)W2P + (size_t)((e * 3 + nt) * 48) * 32768;

    const int tid = threadIdx.x;
    const int lane = tid & 63, w = tid >> 6;
    const int wm = (w >> 2) * 128, wn = (w & 3) * 64;
    const int fr = lane & 15, fq = lane >> 4;
    const int arow_b = (wm + fr) * 128, brow_b = (wn + fr) * 128;
    const int k0 = (fq * 16) ^ ((fr & 7) << 4);

    f32x4 acc[8][4];
#pragma unroll
    for (int i = 0; i < 8; i++)
#pragma unroll
        for (int j = 0; j < 4; j++) acc[i][j] = (f32x4)0.0f;

    mainloopT(At, Bt, 48, 0, smem, tid, arow_b, brow_b, k0, acc);

    const float* b2g = B2 + (size_t)e * HID + (size_t)nt * 256;
    float bias[4];
#pragma unroll
    for (int nj = 0; nj < 4; nj++) bias[nj] = b2g[wn + nj * 16 + fr];
    char* Cgb = (char*)(Out + ((size_t)bs * SEQ + (size_t)mt * 256) * HID + (size_t)nt * 256);

#pragma unroll
    for (int half = 0; half < 2; ++half) {
        if ((wn >> 7) == half) {
#pragma unroll
            for (int mi = 0; mi < 8; mi++)
#pragma unroll
                for (int nj = 0; nj < 4; nj++) {
                    const int lcol = (wn & 127) + nj * 16 + fr;
#pragma unroll
                    for (int r2 = 0; r2 < 4; r2++) {
                        const int row = wm + mi * 16 + fq * 4 + r2;
                        int byte = row * 512 + ((lcol * 4) ^ ((row & 7) << 4));
                        *(float*)(smem + byte) = acc[mi][nj][r2] + bias[nj];
                    }
                }
        }
        __syncthreads();
#pragma unroll
        for (int it = 0; it < 16; it++) {
            int chunk = tid + it * 512;
            int row = chunk >> 5;
            int cb  = (chunk & 31) * 16;
            f32x4 v = *(const f32x4*)(smem + row * 512 + (cb ^ ((row & 7) << 4)));
            __builtin_nontemporal_store(v, (f32x4*)(Cgb + (size_t)row * (HID * 4) + half * 512 + cb));
        }
        if (half == 0) __syncthreads();
    }
}

extern "C" void kernel_launch(void* const* d_in, const int* in_sizes, int n_in,
                              void* d_out, int out_size, void* d_ws, size_t ws_size,
                              hipStream_t stream) {
    const float* X      = (const float*)d_in[0];
    const int*   labels = (const int*)  d_in[1];
    const float* W1     = (const float*)d_in[2];
    const float* B1     = (const float*)d_in[3];
    const float* W2     = (const float*)d_in[4];
    const float* B2     = (const float*)d_in[5];
    float* Out = (float*)d_out;

    char* ws = (char*)d_ws;
    unsigned short* XbP = (unsigned short*)(ws);               // 24 MB used
    unsigned short* W1P = (unsigned short*)(ws + 25165824);    // 36 MB used
    unsigned short* W2P = (unsigned short*)(ws + 62914560);    // 36 MB used
    unsigned short* GP  = (unsigned short*)(ws + 100663296);   // 96 MB used
    int*            perm = (int*)(ws + 201326592);             // 128 B

    (void)hipFuncSetAttribute((const void*)moe_gemm1,
        hipFuncAttributeMaxDynamicSharedMemorySize, 131072);
    (void)hipFuncSetAttribute((const void*)moe_gemm2,
        hipFuncAttributeMaxDynamicSharedMemorySize, 131072);

    // one merged prep launch: sort(1) + cvt_x(768) + cvt_w1(4608) + cvt_w2(4608)
    prep_all<<<1 + 768 + 4608 + 4608, 256, 0, stream>>>(
        X, W1, W2, labels, XbP, W1P, W2P, perm);

    moe_gemm1<<<768, dim3(512), 131072, stream>>>(XbP, labels, perm, W1P, B1, GP);
    moe_gemm2<<<192, dim3(512), 131072, stream>>>(GP, labels, perm, W2P, B2, Out);
}